// Round 5
// baseline (233.669 us; speedup 1.0000x reference)
//
#include <hip/hip_runtime.h>
#include <hip/hip_bf16.h>

// Problem constants
#define NB 32       // B
#define NELEM 16384 // N = B*S
#define DIN 768
#define DMID 128
#define DOUT 4

// Output layout (round-4 forensics): d_out is FLOAT32.
//   ids     f32[16384*2] at offset 0      (row u = {vocab, batch})
//   encoded f32[16384*4] at offset 32768
//
// Sortable 31-bit word: vocab<<14 | e, e = b*512+s.
//   key   = word >> 9   (= vocab*32 + b)
//   idx   = word & 16383
//   vocab = word >> 14, batch = (word>>9) & 31

// ---------------------------------------------------------------------------
// K1: build + in-place single-block radix sort + unique + ids output (f32).
// 512 threads, 32 words each. Workspace: G u32[16384], RS u16[16385].
// ---------------------------------------------------------------------------
__global__ __launch_bounds__(512) void sort_unique_kernel(
    const int* __restrict__ vocab_ids,
    unsigned int* __restrict__ G,
    unsigned short* __restrict__ RS,
    float* __restrict__ out_ids) {
    __shared__ unsigned int hist[512][16];   // 32 KB
    __shared__ unsigned int digitBase[16];
    __shared__ unsigned int partial[512];    // 2 KB
    __shared__ unsigned int totalU;
    const int t = threadIdx.x;

    // build words
    for (int e = t; e < NELEM; e += 512) {
        unsigned int v = (unsigned int)vocab_ids[e];
        G[e] = (v << 14) | (unsigned int)e;
    }
    __syncthreads();

    // 6 LSD passes, 4-bit digits, key bits [9, 33)
    for (int pass = 0; pass < 6; ++pass) {
        const int shift = 9 + pass * 4;
        unsigned int v[32];
#pragma unroll
        for (int i = 0; i < 32; ++i) v[i] = G[t * 32 + i];
#pragma unroll
        for (int d = 0; d < 16; ++d) hist[t][d] = 0;
#pragma unroll
        for (int i = 0; i < 32; ++i) hist[t][(v[i] >> shift) & 15u]++;
        __syncthreads();                // all loads in regs, hists built
        if (t < 16) {                   // scan digit t over 512 threads
            unsigned int run = 0;
            for (int tt = 0; tt < 512; ++tt) {
                unsigned int x = hist[tt][t];
                hist[tt][t] = run;
                run += x;
            }
            digitBase[t] = run;
        }
        __syncthreads();
        if (t == 0) {
            unsigned int run = 0;
            for (int d = 0; d < 16; ++d) {
                unsigned int x = digitBase[d];
                digitBase[d] = run;
                run += x;
            }
        }
        __syncthreads();
        unsigned int mycnt[16];
#pragma unroll
        for (int d = 0; d < 16; ++d) mycnt[d] = hist[t][d] + digitBase[d];
        // in-place scatter: all reads of G for this pass retired before barrier
#pragma unroll
        for (int i = 0; i < 32; ++i) {
            unsigned int d = (v[i] >> shift) & 15u;
            G[mycnt[d]++] = v[i];
        }
        __syncthreads();
    }

    // unique detection -> RS run starts + ids output (f32)
    unsigned int v[32];
#pragma unroll
    for (int i = 0; i < 32; ++i) v[i] = G[t * 32 + i];
    unsigned int prevw = (t == 0) ? 0u : G[t * 32 - 1];
    unsigned int fmask = 0;
#pragma unroll
    for (int i = 0; i < 32; ++i) {
        unsigned int key = v[i] >> 9;
        unsigned int pk = (i == 0) ? (prevw >> 9) : (v[i - 1] >> 9);
        bool f = ((t == 0) && (i == 0)) || (key != pk);
        if (f) fmask |= (1u << i);
    }
    partial[t] = (unsigned int)__popc(fmask);
    __syncthreads();
    if (t == 0) {
        unsigned int run = 0;
        for (int i = 0; i < 512; ++i) {
            unsigned int x = partial[i];
            partial[i] = run;
            run += x;
        }
        totalU = run;
    }
    __syncthreads();
    unsigned int r = partial[t];
#pragma unroll
    for (int i = 0; i < 32; ++i) {
        if ((fmask >> i) & 1u) {
            RS[r] = (unsigned short)(t * 32 + i);
            out_ids[2 * r + 0] = (float)(v[i] >> 14);          // vocab
            out_ids[2 * r + 1] = (float)((v[i] >> 9) & 31u);   // batch
            r++;
        }
    }
    const unsigned int U = totalU;
    for (int u = t; u < NELEM; u += 512) {
        if ((unsigned int)u >= U) {
            RS[u] = (unsigned short)NELEM;
            out_ids[2 * u + 0] = 0.0f;
            out_ids[2 * u + 1] = 0.0f;
        }
    }
    if (t == 0) RS[NELEM] = (unsigned short)NELEM;
}

// ---------------------------------------------------------------------------
// K2: fused gather-sum -> GEMM(tanh) -> per-row encoder dot (sigmoid), f32 out.
// 512 blocks x 256 threads; each block owns 32 unique-slot rows.
// ---------------------------------------------------------------------------
#define BM 32
#define BK 64
__global__ __launch_bounds__(256) void fused_kernel(
    const unsigned int* __restrict__ G,
    const unsigned short* __restrict__ RS,
    const float* __restrict__ emb,
    const float* __restrict__ W1,
    const float* __restrict__ b1,
    const float* __restrict__ enc,
    float* __restrict__ out_enc) {
    __shared__ float As[BM][BK];      // 8 KB
    __shared__ float Ws[BK][DMID];    // 32 KB
    __shared__ float Hs[BM][DMID];    // 16 KB
    const int t = threadIdx.x;
    const int u0 = blockIdx.x * BM;
    const int tr = t >> 4;  // 0..15 -> rows {2tr, 2tr+1}
    const int tc = t & 15;  // 0..15 -> cols {8tc .. 8tc+7}

    float acc[2][8];
#pragma unroll
    for (int i = 0; i < 2; ++i)
#pragma unroll
        for (int j = 0; j < 8; ++j) acc[i][j] = 0.0f;

    for (int kk = 0; kk < DIN; kk += BK) {
        __syncthreads();  // previous compute done before restaging
        // stage A tile: gather-sum embedding rows per unique slot
#pragma unroll
        for (int i = 0; i < 8; ++i) {
            int elem = t + i * 256;         // 0..2047
            int r = elem >> 6;              // row 0..31
            int k = elem & 63;              // col 0..63
            int u = u0 + r;
            int rs = (int)RS[u];
            int re = (int)RS[u + 1];
            float s = 0.0f;
            for (int p = rs; p < re; ++p) {
                unsigned int idx = G[p] & 16383u;
                s += emb[(size_t)idx * DIN + kk + k];
            }
            As[r][k] = s;
        }
        // stage W tile
#pragma unroll
        for (int i = 0; i < 32; ++i) {
            int elem = t + i * 256;         // 0..8191
            int k = elem >> 7;
            int j = elem & 127;
            Ws[k][j] = W1[(size_t)(kk + k) * DMID + j];
        }
        __syncthreads();
#pragma unroll 8
        for (int k = 0; k < BK; ++k) {
            float a0 = As[2 * tr + 0][k];
            float a1 = As[2 * tr + 1][k];
#pragma unroll
            for (int j = 0; j < 8; ++j) {
                float w = Ws[k][tc * 8 + j];
                acc[0][j] += a0 * w;
                acc[1][j] += a1 * w;
            }
        }
    }
    __syncthreads();
    // tanh(acc + b1) -> Hs
#pragma unroll
    for (int i = 0; i < 2; ++i) {
        int r = 2 * tr + i;
#pragma unroll
        for (int j = 0; j < 8; ++j) {
            int c = tc * 8 + j;
            Hs[r][c] = tanhf(acc[i][j] + b1[c]);
        }
    }
    __syncthreads();
    // encode: 32 rows x 4 outputs, dot length 128 against gathered encoder row
    if (t < 128) {
        int r = t >> 2;
        int o = t & 3;
        int u = u0 + r;
        int rs = (int)RS[u];
        int re = (int)RS[u + 1];
        unsigned int vocab = (rs < re) ? (G[rs] >> 14) : 0u;
        const float* w = enc + (size_t)vocab * (DMID * DOUT) + o;
        float s = 0.0f;
#pragma unroll 16
        for (int j = 0; j < DMID; ++j) s += Hs[r][j] * w[j * 4];
        float sg = 1.0f / (1.0f + expf(-s));
        out_enc[(size_t)u * 4 + o] = sg;
    }
}

// ---------------------------------------------------------------------------
extern "C" void kernel_launch(void* const* d_in, const int* in_sizes, int n_in,
                              void* d_out, int out_size, void* d_ws, size_t ws_size,
                              hipStream_t stream) {
    const int*   vocab_ids = (const int*)d_in[0];
    const float* emb       = (const float*)d_in[1];
    const float* W1        = (const float*)d_in[2];
    const float* b1        = (const float*)d_in[3];
    const float* enc       = (const float*)d_in[4];
    float* out = (float*)d_out;

    float* out_ids = out;               // 32768 f32
    float* out_enc = out + NELEM * 2;   // 65536 f32

    char* ws = (char*)d_ws;
    unsigned int*   G  = (unsigned int*)(ws + 0);        // 65,536 B
    unsigned short* RS = (unsigned short*)(ws + 65536);  // 32,770 B

    sort_unique_kernel<<<1, 512, 0, stream>>>(vocab_ids, G, RS, out_ids);
    fused_kernel<<<NELEM / BM, 256, 0, stream>>>(G, RS, emb, W1, b1, enc, out_enc);
}

// Round 6
// 156.980 us; speedup vs baseline: 1.4885x; 1.4885x over previous
//
#include <hip/hip_runtime.h>
#include <hip/hip_bf16.h>

#define NELEM 16384
#define DIN 768
#define DMID 128
#define DOUT 4

typedef __attribute__((ext_vector_type(8))) short short8;
typedef __attribute__((ext_vector_type(4))) float f32x4;

__device__ __forceinline__ unsigned f2bf(float f) {
    unsigned u = __float_as_uint(f);
    return (u + 0x7FFFu + ((u >> 16) & 1u)) >> 16;   // RNE bf16
}

// ---------------------------------------------------------------------------
// K1: block 0 = LDS-resident radix sort + unique + ids; blocks 1..96 = W1^T->bf16.
// word = vocab<<14 | e (e = b*512+s); key = word>>9; idx = word&16383.
// Dynamic LDS: Gs u32[16384] @0; histDM u32[16*1024] @65536 (digit-major:
// index d*1024+t); sums u32[1024] @131072; totalU @135168.
// ---------------------------------------------------------------------------
#define SORT_SMEM (65536 + 65536 + 4096 + 64)

__global__ __launch_bounds__(1024) void sort_transpose_kernel(
    const int* __restrict__ vocab_ids,
    const float* __restrict__ W1,
    unsigned int* __restrict__ G,
    unsigned short* __restrict__ RS,
    unsigned short* __restrict__ WtG,
    float* __restrict__ out_ids) {
    const int t = threadIdx.x;
    if (blockIdx.x != 0) {
        // transpose W1 (768x128 f32) -> WtG (128x768 bf16); writes coalesced
        int idx = (blockIdx.x - 1) * 1024 + t;
        if (idx < DMID * DIN) {
            int c = idx / DIN;
            int k = idx - c * DIN;
            WtG[idx] = (unsigned short)f2bf(W1[k * DMID + c]);
        }
        return;
    }
    extern __shared__ char smem[];
    unsigned* Gs     = (unsigned*)smem;
    unsigned* histDM = (unsigned*)(smem + 65536);
    unsigned* sums   = (unsigned*)(smem + 131072);
    unsigned* totalU = (unsigned*)(smem + 135168);

    for (int e = t; e < NELEM; e += 1024)
        Gs[e] = ((unsigned)vocab_ids[e] << 14) | (unsigned)e;
    __syncthreads();

    // 6 LSD passes, 4-bit digits, key bits [9,33)
    for (int pass = 0; pass < 6; ++pass) {
        const int shift = 9 + pass * 4;
        unsigned v[16];
#pragma unroll
        for (int i = 0; i < 16; ++i) v[i] = Gs[t * 16 + i];
#pragma unroll
        for (int d = 0; d < 16; ++d) histDM[d * 1024 + t] = 0;
#pragma unroll
        for (int i = 0; i < 16; ++i) histDM[((v[i] >> shift) & 15u) * 1024 + t] += 1;
        __syncthreads();
        // chunk-local exclusive scan (chunk t = linear positions [t*16, t*16+16))
        unsigned lex[16]; unsigned run = 0;
#pragma unroll
        for (int i = 0; i < 16; ++i) { unsigned x = histDM[t * 16 + i]; lex[i] = run; run += x; }
        sums[t] = run;
        __syncthreads();
        if (t < 64) {   // single wave scans the 1024 chunk-sums
            unsigned s[16]; unsigned tot = 0;
#pragma unroll
            for (int i = 0; i < 16; ++i) { unsigned x = sums[t * 16 + i]; s[i] = tot; tot += x; }
            unsigned inc = tot;
#pragma unroll
            for (int off = 1; off < 64; off <<= 1) {
                unsigned y = __shfl_up(inc, off);
                if (t >= off) inc += y;
            }
            unsigned excl = inc - tot;
#pragma unroll
            for (int i = 0; i < 16; ++i) sums[t * 16 + i] = excl + s[i];
        }
        __syncthreads();
#pragma unroll
        for (int i = 0; i < 16; ++i) histDM[t * 16 + i] = sums[t] + lex[i];
        __syncthreads();
        unsigned mycnt[16];
#pragma unroll
        for (int d = 0; d < 16; ++d) mycnt[d] = histDM[d * 1024 + t];
#pragma unroll
        for (int i = 0; i < 16; ++i) {
            unsigned d = (v[i] >> shift) & 15u;
            Gs[mycnt[d]++] = v[i];
        }
        __syncthreads();
    }

    // unique detection + RS + ids + write sorted G out
    unsigned v[16];
#pragma unroll
    for (int i = 0; i < 16; ++i) v[i] = Gs[t * 16 + i];
    unsigned pk = (t == 0) ? 0xFFFFFFFFu : (Gs[t * 16 - 1] >> 9);
    unsigned fm = 0;
#pragma unroll
    for (int i = 0; i < 16; ++i) {
        unsigned key = v[i] >> 9;
        if (key != pk) fm |= (1u << i);
        pk = key;
    }
    sums[t] = (unsigned)__popc(fm);
    __syncthreads();
    if (t < 64) {
        unsigned s[16]; unsigned tot = 0;
#pragma unroll
        for (int i = 0; i < 16; ++i) { unsigned x = sums[t * 16 + i]; s[i] = tot; tot += x; }
        unsigned inc = tot;
#pragma unroll
        for (int off = 1; off < 64; off <<= 1) {
            unsigned y = __shfl_up(inc, off);
            if (t >= off) inc += y;
        }
        unsigned excl = inc - tot;
#pragma unroll
        for (int i = 0; i < 16; ++i) sums[t * 16 + i] = excl + s[i];
        if (t == 63) *totalU = inc;
    }
    __syncthreads();
    unsigned r = sums[t];
#pragma unroll
    for (int i = 0; i < 16; ++i) {
        if (fm & (1u << i)) {
            RS[r] = (unsigned short)(t * 16 + i);
            out_ids[2 * r + 0] = (float)(v[i] >> 14);
            out_ids[2 * r + 1] = (float)((v[i] >> 9) & 31u);
            ++r;
        }
    }
    const unsigned U = *totalU;
    for (int u = t; u < NELEM; u += 1024) {
        if ((unsigned)u >= U) {
            RS[u] = (unsigned short)NELEM;
            out_ids[2 * u + 0] = 0.0f;
            out_ids[2 * u + 1] = 0.0f;
        }
        G[u] = Gs[u];
    }
    if (t == 0) RS[NELEM] = (unsigned short)NELEM;
}

// ---------------------------------------------------------------------------
// K2: MFMA fused kernel. 1024 blocks x 256 threads; 16 rows/block.
// LDS: As bf16[16][72] @0 (2304B); Wt_s bf16[128][72] @2304 (18432B);
//      Hs f32[16][132] overlays @0 after GEMM. Union = 20736 B.
// mfma_f32_16x16x32_bf16: A lane l holds row l&15, k=(l>>4)*8+e (contig 16B);
// B lane l holds col l&15, k=(l>>4)*8+e; D: col=l&15, row=(l>>4)*4+reg.
// ---------------------------------------------------------------------------
#define FBM 16
__global__ __launch_bounds__(256) void fused_kernel(
    const unsigned* __restrict__ G,
    const unsigned short* __restrict__ RS,
    const unsigned short* __restrict__ WtG,
    const float* __restrict__ emb,
    const float* __restrict__ b1,
    const float* __restrict__ enc,
    float* __restrict__ out_enc) {
    __shared__ char smem[20736];

    const int t = threadIdx.x;
    const int u0 = blockIdx.x * FBM;
    const int l = t & 63;
    const int w = t >> 6;

    // A-stage cell: row ar (0..15), k-quad ak4 (0..15) -> k = ak4*4..+4
    const int ar = t >> 4;
    const int ak4 = t & 15;
    const int rs_a = (int)RS[u0 + ar];
    const int re_a = (int)RS[u0 + ar + 1];

    f32x4 acc0 = {0.f, 0.f, 0.f, 0.f};
    f32x4 acc1 = {0.f, 0.f, 0.f, 0.f};

    for (int kk = 0; kk < DIN; kk += 64) {
        __syncthreads();
        // ---- A-stage: gather-sum 4 consecutive k, convert bf16, store (pad-72 rows)
        {
            float s0 = 0.f, s1 = 0.f, s2 = 0.f, s3 = 0.f;
            const float* base = emb + (size_t)(kk + ak4 * 4);
            for (int p = rs_a; p < re_a; ++p) {
                unsigned idx = G[p] & 16383u;
                const float4 e4 = *(const float4*)(base + (size_t)idx * DIN);
                s0 += e4.x; s1 += e4.y; s2 += e4.z; s3 += e4.w;
            }
            uint2 packed;
            packed.x = f2bf(s0) | (f2bf(s1) << 16);
            packed.y = f2bf(s2) | (f2bf(s3) << 16);
            *(uint2*)(smem + ar * 144 + ak4 * 8) = packed;
        }
        // ---- W-stage: 4x 16B units per thread from pre-transposed bf16 W^T
        {
#pragma unroll
            for (int i = 0; i < 4; ++i) {
                int q = t + i * 256;       // 0..1023
                int c = q >> 3;            // 0..127
                int uo = q & 7;            // 16B unit (8 bf16)
                uint4 dv = *(const uint4*)(WtG + (size_t)c * DIN + kk + uo * 8);
                *(uint4*)(smem + 2304 + c * 144 + uo * 16) = dv;
            }
        }
        __syncthreads();
        // ---- MFMA: per wave, 16 rows x 32 cols (c0 = w*32), BK=64 = 2 K-frags
        {
            const int arow = l & 15;
            const int ull = l >> 4;
#pragma unroll
            for (int kf = 0; kf < 2; ++kf) {
                short8 aF = *(const short8*)(smem + arow * 144 + kf * 64 + ull * 16);
                short8 bF0 = *(const short8*)(smem + 2304 + (w * 32 + arow) * 144 + kf * 64 + ull * 16);
                short8 bF1 = *(const short8*)(smem + 2304 + (w * 32 + 16 + arow) * 144 + kf * 64 + ull * 16);
                acc0 = __builtin_amdgcn_mfma_f32_16x16x32_bf16(aF, bF0, acc0, 0, 0, 0);
                acc1 = __builtin_amdgcn_mfma_f32_16x16x32_bf16(aF, bF1, acc1, 0, 0, 0);
            }
        }
    }
    __syncthreads();
    // ---- epilogue: bias + tanh -> Hs (f32, stride 132)
    {
        float* Hs = (float*)smem;
        const int col0 = w * 32 + (l & 15);
        const int rbase = (l >> 4) * 4;
#pragma unroll
        for (int reg = 0; reg < 4; ++reg) {
            Hs[(rbase + reg) * 132 + col0] = tanhf(acc0[reg] + b1[col0]);
            Hs[(rbase + reg) * 132 + col0 + 16] = tanhf(acc1[reg] + b1[col0 + 16]);
        }
    }
    __syncthreads();
    // ---- encoder: 16 threads per row, 8 j's each, shuffle-reduce, sigmoid
    {
        const float* Hs = (const float*)smem;
        const int r = t >> 4;
        const int g = t & 15;
        const int u = u0 + r;
        const int rs = (int)RS[u];
        const int re = (int)RS[u + 1];
        unsigned vocab = (rs < re) ? (G[rs] >> 14) : 0u;
        const float4* wrow = (const float4*)(enc + (size_t)vocab * (DMID * DOUT));
        float ax = 0.f, ay = 0.f, az = 0.f, aw = 0.f;
#pragma unroll
        for (int jj = 0; jj < 8; ++jj) {
            int j = jj * 16 + g;
            float4 w4 = wrow[j];
            float hv = Hs[r * 132 + j];
            ax += hv * w4.x; ay += hv * w4.y; az += hv * w4.z; aw += hv * w4.w;
        }
#pragma unroll
        for (int off = 1; off < 16; off <<= 1) {
            ax += __shfl_xor(ax, off);
            ay += __shfl_xor(ay, off);
            az += __shfl_xor(az, off);
            aw += __shfl_xor(aw, off);
        }
        if (g == 0) {
            float4 o;
            o.x = 1.f / (1.f + expf(-ax));
            o.y = 1.f / (1.f + expf(-ay));
            o.z = 1.f / (1.f + expf(-az));
            o.w = 1.f / (1.f + expf(-aw));
            *(float4*)(out_enc + (size_t)u * 4) = o;
        }
    }
}

// ---------------------------------------------------------------------------
extern "C" void kernel_launch(void* const* d_in, const int* in_sizes, int n_in,
                              void* d_out, int out_size, void* d_ws, size_t ws_size,
                              hipStream_t stream) {
    const int*   vocab_ids = (const int*)d_in[0];
    const float* emb       = (const float*)d_in[1];
    const float* W1        = (const float*)d_in[2];
    const float* b1        = (const float*)d_in[3];
    const float* enc       = (const float*)d_in[4];
    float* out = (float*)d_out;

    float* out_ids = out;               // 32768 f32
    float* out_enc = out + NELEM * 2;   // 65536 f32

    char* ws = (char*)d_ws;
    unsigned int*   G   = (unsigned int*)(ws);            // 65,536 B
    unsigned short* RS  = (unsigned short*)(ws + 65536);  // 32,772 B
    unsigned short* WtG = (unsigned short*)(ws + 98432);  // 196,608 B (ends 295,040)

    hipFuncSetAttribute((const void*)sort_transpose_kernel,
                        hipFuncAttributeMaxDynamicSharedMemorySize, SORT_SMEM);

    sort_transpose_kernel<<<1 + 96, 1024, SORT_SMEM, stream>>>(
        vocab_ids, W1, G, RS, WtG, out_ids);
    fused_kernel<<<NELEM / FBM, 256, 0, stream>>>(
        G, RS, WtG, emb, b1, enc, out_enc);
}

// Round 7
// 71.122 us; speedup vs baseline: 3.2855x; 2.2072x over previous
//
#include <hip/hip_runtime.h>
#include <hip/hip_bf16.h>

#define NELEM 16384
#define DIN 768
#define DMID 128
#define DOUT 4

typedef __attribute__((ext_vector_type(8))) short short8;
typedef __attribute__((ext_vector_type(4))) float f32x4;

__device__ __forceinline__ unsigned f2bf(float f) {
    unsigned u = __float_as_uint(f);
    return (u + 0x7FFFu + ((u >> 16) & 1u)) >> 16;   // RNE bf16
}

// word = vocab<<14 | e (e = b*512+s); key = word>>9; idx = word&16383;
// vocab = word>>14; batch = (word>>9)&31.

// ===========================================================================
// FAST PATH: parallel 3-pass LSD radix (8-bit digits over key bits [9,33)).
// ws layout: P0@0(64K) P1@65536(64K) hist0@131072(64K) hist1@196608(64K)
//            hist2@262144(64K) RS@327680(32772B) WtG@360512(192K) end 557120.
// hist layout: hist[d*64 + block], 64 blocks x 256 elements.
// ===========================================================================
#define FAST_WS 557120

// K1: blocks 0..63: build words + pass-0 hist + zero hist1/2. 64..447: W1^T->bf16.
__global__ __launch_bounds__(256) void prep_kernel(
    const int* __restrict__ vocab_ids, const float* __restrict__ W1,
    unsigned* __restrict__ P0, unsigned* __restrict__ hist0,
    unsigned* __restrict__ histZ, unsigned short* __restrict__ WtG) {
    const int t = threadIdx.x;
    const int bx = blockIdx.x;
    if (bx < 64) {
        __shared__ unsigned h[256];
        h[t] = 0;
        int e = bx * 256 + t;
        unsigned word = ((unsigned)vocab_ids[e] << 14) | (unsigned)e;
        P0[e] = word;
        __syncthreads();
        atomicAdd(&h[(word >> 9) & 255u], 1u);   // LDS atomic: deterministic count
        __syncthreads();
        hist0[t * 64 + bx] = h[t];
        histZ[bx * 512 + t] = 0;                 // zero hist1+hist2 (32768 u32)
        histZ[bx * 512 + 256 + t] = 0;
    } else {
        int idx = (bx - 64) * 256 + t;           // 0..98303
        int c = idx / DIN;
        int k = idx - c * DIN;
        WtG[idx] = (unsigned short)f2bf(W1[k * DMID + c]);
    }
}

// K2/3/4: scatter pass. Redundant per-block scan of hist (digit t per thread),
// stable rank via 8-ballot match + per-wave LDS hist. Optionally builds the
// next pass's hist with order-independent global atomics.
template <int SHIFT, int NSHIFT, bool HASNEXT>
__global__ __launch_bounds__(256) void scatter_kernel(
    const unsigned* __restrict__ src, unsigned* __restrict__ dst,
    const unsigned* __restrict__ histCur, unsigned* __restrict__ histNext) {
    __shared__ unsigned base_lds[256];
    __shared__ unsigned whist[4 * 256];
    __shared__ unsigned wsum[4];
    const int t = threadIdx.x;
    const int blk = blockIdx.x;
    const int lane = t & 63;
    const int w = t >> 6;

    unsigned x = src[blk * 256 + t];
    unsigned d = (x >> SHIFT) & 255u;

    whist[t] = 0; whist[256 + t] = 0; whist[512 + t] = 0; whist[768 + t] = 0;

    // digit-row scan: rowsum (all blocks) + prefix over blocks < blk
    unsigned rowsum = 0, myprefix = 0;
    const uint4* row = (const uint4*)(histCur + t * 64);
#pragma unroll
    for (int q = 0; q < 16; ++q) {
        uint4 h4 = row[q];
        int b = q * 4;
        rowsum += h4.x + h4.y + h4.z + h4.w;
        if (b + 0 < blk) myprefix += h4.x;
        if (b + 1 < blk) myprefix += h4.y;
        if (b + 2 < blk) myprefix += h4.z;
        if (b + 3 < blk) myprefix += h4.w;
    }
    // block-exclusive scan of the 256 rowsums (digit-major => global digit base)
    unsigned inc = rowsum;
#pragma unroll
    for (int off = 1; off < 64; off <<= 1) {
        unsigned y = __shfl_up(inc, off);
        if (lane >= off) inc += y;
    }
    if (lane == 63) wsum[w] = inc;
    __syncthreads();
    unsigned wo = 0;
    for (int w2 = 0; w2 < w; ++w2) wo += wsum[w2];
    base_lds[t] = wo + (inc - rowsum) + myprefix;

    // stable in-wave rank via match-any (8 ballots)
    unsigned long long m = ~0ull;
#pragma unroll
    for (int bit = 0; bit < 8; ++bit) {
        unsigned long long bb = __ballot((d >> bit) & 1u);
        m &= ((d >> bit) & 1u) ? bb : ~bb;
    }
    int inrank = __popcll(m & ((1ull << lane) - 1ull));
    if (inrank == 0) whist[w * 256 + d] = (unsigned)__popcll(m);
    __syncthreads();
    unsigned cross = 0;
    for (int w2 = 0; w2 < w; ++w2) cross += whist[w2 * 256 + d];
    unsigned dstpos = base_lds[d] + cross + (unsigned)inrank;
    dst[dstpos] = x;
    if (HASNEXT) {
        unsigned dn = (x >> NSHIFT) & 255u;
        atomicAdd(&histNext[dn * 64 + (dstpos >> 8)], 1u);  // count: deterministic
    }
}

// K5: unique + RS + ids (1 block, 1024 threads, 16 sorted elems each)
__global__ __launch_bounds__(1024) void unique_kernel(
    const unsigned* __restrict__ P, unsigned short* __restrict__ RS,
    float* __restrict__ out_ids) {
    __shared__ unsigned sums[1024];
    __shared__ unsigned totalU;
    const int t = threadIdx.x;
    unsigned v[16];
    const uint4* p4 = (const uint4*)(P + t * 16);
#pragma unroll
    for (int q = 0; q < 4; ++q) {
        uint4 x = p4[q];
        v[q * 4] = x.x; v[q * 4 + 1] = x.y; v[q * 4 + 2] = x.z; v[q * 4 + 3] = x.w;
    }
    unsigned pk = (t == 0) ? 0xFFFFFFFFu : (P[t * 16 - 1] >> 9);
    unsigned fm = 0;
#pragma unroll
    for (int i = 0; i < 16; ++i) {
        unsigned key = v[i] >> 9;
        if (key != pk) fm |= (1u << i);
        pk = key;
    }
    sums[t] = (unsigned)__popc(fm);
    __syncthreads();
    if (t < 64) {
        unsigned s[16]; unsigned tot = 0;
#pragma unroll
        for (int i = 0; i < 16; ++i) { unsigned x = sums[t * 16 + i]; s[i] = tot; tot += x; }
        unsigned incv = tot;
#pragma unroll
        for (int off = 1; off < 64; off <<= 1) {
            unsigned y = __shfl_up(incv, off);
            if (t >= off) incv += y;
        }
        unsigned excl = incv - tot;
#pragma unroll
        for (int i = 0; i < 16; ++i) sums[t * 16 + i] = excl + s[i];
        if (t == 63) totalU = incv;
    }
    __syncthreads();
    unsigned r = sums[t];
#pragma unroll
    for (int i = 0; i < 16; ++i) {
        if (fm & (1u << i)) {
            RS[r] = (unsigned short)(t * 16 + i);
            out_ids[2 * r + 0] = (float)(v[i] >> 14);
            out_ids[2 * r + 1] = (float)((v[i] >> 9) & 31u);
            ++r;
        }
    }
    const unsigned U = totalU;
    for (int u = t; u < NELEM; u += 1024) {
        if ((unsigned)u >= U) {
            RS[u] = (unsigned short)NELEM;
            out_ids[2 * u + 0] = 0.0f;
            out_ids[2 * u + 1] = 0.0f;
        }
    }
    if (t == 0) RS[NELEM] = (unsigned short)NELEM;
}

// ===========================================================================
// FALLBACK (proven R6 path): single-block LDS sort + transpose, if ws small.
// ===========================================================================
#define SORT_SMEM (65536 + 65536 + 4096 + 64)

__global__ __launch_bounds__(1024) void sort_transpose_kernel(
    const int* __restrict__ vocab_ids,
    const float* __restrict__ W1,
    unsigned int* __restrict__ G,
    unsigned short* __restrict__ RS,
    unsigned short* __restrict__ WtG,
    float* __restrict__ out_ids) {
    const int t = threadIdx.x;
    if (blockIdx.x != 0) {
        int idx = (blockIdx.x - 1) * 1024 + t;
        if (idx < DMID * DIN) {
            int c = idx / DIN;
            int k = idx - c * DIN;
            WtG[idx] = (unsigned short)f2bf(W1[k * DMID + c]);
        }
        return;
    }
    extern __shared__ char smem[];
    unsigned* Gs     = (unsigned*)smem;
    unsigned* histDM = (unsigned*)(smem + 65536);
    unsigned* sums   = (unsigned*)(smem + 131072);
    unsigned* totalU = (unsigned*)(smem + 135168);

    for (int e = t; e < NELEM; e += 1024)
        Gs[e] = ((unsigned)vocab_ids[e] << 14) | (unsigned)e;
    __syncthreads();

    for (int pass = 0; pass < 6; ++pass) {
        const int shift = 9 + pass * 4;
        unsigned v[16];
#pragma unroll
        for (int i = 0; i < 16; ++i) v[i] = Gs[t * 16 + i];
#pragma unroll
        for (int d = 0; d < 16; ++d) histDM[d * 1024 + t] = 0;
#pragma unroll
        for (int i = 0; i < 16; ++i) histDM[((v[i] >> shift) & 15u) * 1024 + t] += 1;
        __syncthreads();
        unsigned lex[16]; unsigned run = 0;
#pragma unroll
        for (int i = 0; i < 16; ++i) { unsigned x = histDM[t * 16 + i]; lex[i] = run; run += x; }
        sums[t] = run;
        __syncthreads();
        if (t < 64) {
            unsigned s[16]; unsigned tot = 0;
#pragma unroll
            for (int i = 0; i < 16; ++i) { unsigned x = sums[t * 16 + i]; s[i] = tot; tot += x; }
            unsigned incv = tot;
#pragma unroll
            for (int off = 1; off < 64; off <<= 1) {
                unsigned y = __shfl_up(incv, off);
                if (t >= off) incv += y;
            }
            unsigned excl = incv - tot;
#pragma unroll
            for (int i = 0; i < 16; ++i) sums[t * 16 + i] = excl + s[i];
        }
        __syncthreads();
#pragma unroll
        for (int i = 0; i < 16; ++i) histDM[t * 16 + i] = sums[t] + lex[i];
        __syncthreads();
        unsigned mycnt[16];
#pragma unroll
        for (int d = 0; d < 16; ++d) mycnt[d] = histDM[d * 1024 + t];
#pragma unroll
        for (int i = 0; i < 16; ++i) {
            unsigned d = (v[i] >> shift) & 15u;
            Gs[mycnt[d]++] = v[i];
        }
        __syncthreads();
    }

    unsigned v[16];
#pragma unroll
    for (int i = 0; i < 16; ++i) v[i] = Gs[t * 16 + i];
    unsigned pk = (t == 0) ? 0xFFFFFFFFu : (Gs[t * 16 - 1] >> 9);
    unsigned fm = 0;
#pragma unroll
    for (int i = 0; i < 16; ++i) {
        unsigned key = v[i] >> 9;
        if (key != pk) fm |= (1u << i);
        pk = key;
    }
    sums[t] = (unsigned)__popc(fm);
    __syncthreads();
    if (t < 64) {
        unsigned s[16]; unsigned tot = 0;
#pragma unroll
        for (int i = 0; i < 16; ++i) { unsigned x = sums[t * 16 + i]; s[i] = tot; tot += x; }
        unsigned incv = tot;
#pragma unroll
        for (int off = 1; off < 64; off <<= 1) {
            unsigned y = __shfl_up(incv, off);
            if (t >= off) incv += y;
        }
        unsigned excl = incv - tot;
#pragma unroll
        for (int i = 0; i < 16; ++i) sums[t * 16 + i] = excl + s[i];
        if (t == 63) *totalU = incv;
    }
    __syncthreads();
    unsigned r = sums[t];
#pragma unroll
    for (int i = 0; i < 16; ++i) {
        if (fm & (1u << i)) {
            RS[r] = (unsigned short)(t * 16 + i);
            out_ids[2 * r + 0] = (float)(v[i] >> 14);
            out_ids[2 * r + 1] = (float)((v[i] >> 9) & 31u);
            ++r;
        }
    }
    const unsigned U = *totalU;
    for (int u = t; u < NELEM; u += 1024) {
        if ((unsigned)u >= U) {
            RS[u] = (unsigned short)NELEM;
            out_ids[2 * u + 0] = 0.0f;
            out_ids[2 * u + 1] = 0.0f;
        }
        G[u] = Gs[u];
    }
    if (t == 0) RS[NELEM] = (unsigned short)NELEM;
}

// ===========================================================================
// K6: MFMA fused kernel (unchanged from R6). 1024 blocks x 256 thr, 16 rows.
// ===========================================================================
#define FBM 16
__global__ __launch_bounds__(256) void fused_kernel(
    const unsigned* __restrict__ G,
    const unsigned short* __restrict__ RS,
    const unsigned short* __restrict__ WtG,
    const float* __restrict__ emb,
    const float* __restrict__ b1,
    const float* __restrict__ enc,
    float* __restrict__ out_enc) {
    __shared__ char smem[20736];

    const int t = threadIdx.x;
    const int u0 = blockIdx.x * FBM;
    const int l = t & 63;
    const int w = t >> 6;

    const int ar = t >> 4;
    const int ak4 = t & 15;
    const int rs_a = (int)RS[u0 + ar];
    const int re_a = (int)RS[u0 + ar + 1];

    f32x4 acc0 = {0.f, 0.f, 0.f, 0.f};
    f32x4 acc1 = {0.f, 0.f, 0.f, 0.f};

    for (int kk = 0; kk < DIN; kk += 64) {
        __syncthreads();
        {
            float s0 = 0.f, s1 = 0.f, s2 = 0.f, s3 = 0.f;
            const float* base = emb + (size_t)(kk + ak4 * 4);
            for (int p = rs_a; p < re_a; ++p) {
                unsigned idx = G[p] & 16383u;
                const float4 e4 = *(const float4*)(base + (size_t)idx * DIN);
                s0 += e4.x; s1 += e4.y; s2 += e4.z; s3 += e4.w;
            }
            uint2 packed;
            packed.x = f2bf(s0) | (f2bf(s1) << 16);
            packed.y = f2bf(s2) | (f2bf(s3) << 16);
            *(uint2*)(smem + ar * 144 + ak4 * 8) = packed;
        }
        {
#pragma unroll
            for (int i = 0; i < 4; ++i) {
                int q = t + i * 256;
                int c = q >> 3;
                int uo = q & 7;
                uint4 dv = *(const uint4*)(WtG + (size_t)c * DIN + kk + uo * 8);
                *(uint4*)(smem + 2304 + c * 144 + uo * 16) = dv;
            }
        }
        __syncthreads();
        {
            const int arow = l & 15;
            const int ull = l >> 4;
#pragma unroll
            for (int kf = 0; kf < 2; ++kf) {
                short8 aF = *(const short8*)(smem + arow * 144 + kf * 64 + ull * 16);
                short8 bF0 = *(const short8*)(smem + 2304 + (w * 32 + arow) * 144 + kf * 64 + ull * 16);
                short8 bF1 = *(const short8*)(smem + 2304 + (w * 32 + 16 + arow) * 144 + kf * 64 + ull * 16);
                acc0 = __builtin_amdgcn_mfma_f32_16x16x32_bf16(aF, bF0, acc0, 0, 0, 0);
                acc1 = __builtin_amdgcn_mfma_f32_16x16x32_bf16(aF, bF1, acc1, 0, 0, 0);
            }
        }
    }
    __syncthreads();
    {
        float* Hs = (float*)smem;
        const int col0 = w * 32 + (l & 15);
        const int rbase = (l >> 4) * 4;
#pragma unroll
        for (int reg = 0; reg < 4; ++reg) {
            Hs[(rbase + reg) * 132 + col0] = tanhf(acc0[reg] + b1[col0]);
            Hs[(rbase + reg) * 132 + col0 + 16] = tanhf(acc1[reg] + b1[col0 + 16]);
        }
    }
    __syncthreads();
    {
        const float* Hs = (const float*)smem;
        const int r = t >> 4;
        const int g = t & 15;
        const int u = u0 + r;
        const int rs = (int)RS[u];
        const int re = (int)RS[u + 1];
        unsigned vocab = (rs < re) ? (G[rs] >> 14) : 0u;
        const float4* wrow = (const float4*)(enc + (size_t)vocab * (DMID * DOUT));
        float ax = 0.f, ay = 0.f, az = 0.f, aw = 0.f;
#pragma unroll
        for (int jj = 0; jj < 8; ++jj) {
            int j = jj * 16 + g;
            float4 w4 = wrow[j];
            float hv = Hs[r * 132 + j];
            ax += hv * w4.x; ay += hv * w4.y; az += hv * w4.z; aw += hv * w4.w;
        }
#pragma unroll
        for (int off = 1; off < 16; off <<= 1) {
            ax += __shfl_xor(ax, off);
            ay += __shfl_xor(ay, off);
            az += __shfl_xor(az, off);
            aw += __shfl_xor(aw, off);
        }
        if (g == 0) {
            float4 o;
            o.x = 1.f / (1.f + expf(-ax));
            o.y = 1.f / (1.f + expf(-ay));
            o.z = 1.f / (1.f + expf(-az));
            o.w = 1.f / (1.f + expf(-aw));
            *(float4*)(out_enc + (size_t)u * 4) = o;
        }
    }
}

// ---------------------------------------------------------------------------
extern "C" void kernel_launch(void* const* d_in, const int* in_sizes, int n_in,
                              void* d_out, int out_size, void* d_ws, size_t ws_size,
                              hipStream_t stream) {
    const int*   vocab_ids = (const int*)d_in[0];
    const float* emb       = (const float*)d_in[1];
    const float* W1        = (const float*)d_in[2];
    const float* b1        = (const float*)d_in[3];
    const float* enc       = (const float*)d_in[4];
    float* out = (float*)d_out;

    float* out_ids = out;               // 32768 f32
    float* out_enc = out + NELEM * 2;   // 65536 f32

    char* ws = (char*)d_ws;

    if (ws_size >= FAST_WS) {
        unsigned*       P0    = (unsigned*)(ws + 0);
        unsigned*       P1    = (unsigned*)(ws + 65536);
        unsigned*       hist0 = (unsigned*)(ws + 131072);
        unsigned*       hist1 = (unsigned*)(ws + 196608);
        unsigned*       hist2 = (unsigned*)(ws + 262144);
        unsigned short* RS    = (unsigned short*)(ws + 327680);
        unsigned short* WtG   = (unsigned short*)(ws + 360512);

        prep_kernel<<<448, 256, 0, stream>>>(vocab_ids, W1, P0, hist0, hist1, WtG);
        scatter_kernel<9, 17, true><<<64, 256, 0, stream>>>(P0, P1, hist0, hist1);
        scatter_kernel<17, 25, true><<<64, 256, 0, stream>>>(P1, P0, hist1, hist2);
        scatter_kernel<25, 0, false><<<64, 256, 0, stream>>>(P0, P1, hist2, nullptr);
        unique_kernel<<<1, 1024, 0, stream>>>(P1, RS, out_ids);
        fused_kernel<<<NELEM / FBM, 256, 0, stream>>>(P1, RS, WtG, emb, b1, enc, out_enc);
    } else {
        unsigned int*   G   = (unsigned int*)(ws);
        unsigned short* RS  = (unsigned short*)(ws + 65536);
        unsigned short* WtG = (unsigned short*)(ws + 98432);

        hipFuncSetAttribute((const void*)sort_transpose_kernel,
                            hipFuncAttributeMaxDynamicSharedMemorySize, SORT_SMEM);
        sort_transpose_kernel<<<1 + 96, 1024, SORT_SMEM, stream>>>(
            vocab_ids, W1, G, RS, WtG, out_ids);
        fused_kernel<<<NELEM / FBM, 256, 0, stream>>>(G, RS, WtG, emb, b1, enc, out_enc);
    }
}